// Round 8
// baseline (164.167 us; speedup 1.0000x reference)
//
#include <hip/hip_runtime.h>
#include <hip/hip_bf16.h>
#include <cmath>

#define NB   4
#define NS   1024
#define NHID 1024
#define NH   16
#define NDH  64
#define QKV_PLANE (NB * NH * NS * NDH)   // elements per q/k/v plane

typedef __attribute__((ext_vector_type(8))) short bf16x8;
typedef __attribute__((ext_vector_type(4))) float f32x4;
typedef __attribute__((ext_vector_type(8))) unsigned short u16x8;

typedef __attribute__((address_space(1))) const void gv_t;
typedef __attribute__((address_space(3))) void       lv_t;

__device__ __forceinline__ void gload16(const void* g, void* l) {
    // async global->LDS, 16B/lane; LDS dest = wave-uniform base + lane*16,
    // global address is per-lane arbitrary (lets us swizzle the LDS layout).
    __builtin_amdgcn_global_load_lds((gv_t*)g, (lv_t*)l, 16, 0, 0);
}

__device__ __forceinline__ unsigned short f2b(float f) {
    union { float f; unsigned int u; } v; v.f = f;
    unsigned int r = (v.u + 0x7fff + ((v.u >> 16) & 1)) >> 16;   // RNE
    return (unsigned short)r;
}

// packed fp32x2 -> bf16x2 (RNE); lo 16 bits = a
__device__ __forceinline__ unsigned int f2b2(float a, float b) {
    __hip_bfloat162 h = __float22bfloat162_rn(make_float2(a, b));
    union { __hip_bfloat162 h; unsigned int u; } v; v.h = h;
    return v.u;
}

__device__ __forceinline__ float fexp2(float x) {
#if __has_builtin(__builtin_amdgcn_exp2f)
    return __builtin_amdgcn_exp2f(x);
#else
    return exp2f(x);
#endif
}

// ---------------------------------------------------------------------------
// Prep (single launch, grid (16,16,5)):
//  z<3 : cast+transpose Wq/Wk/Wv [K][N] fp32 -> wt [z*1024+n][k] bf16
//  z==3: cast hidden_states fp32 -> bf16 row-major [4096][1024]
//  z==4: RoPE table cs[s][d] = (cos,sin)(freqs[s][d]), d<32  (float2[1024][32])
// ---------------------------------------------------------------------------
__global__ __launch_bounds__(256) void prep_kernel(
    const float* __restrict__ hs, const float* __restrict__ freqs,
    const float* __restrict__ Wq, const float* __restrict__ Wk,
    const float* __restrict__ Wv,
    unsigned short* __restrict__ hsb, unsigned short* __restrict__ wt,
    float2* __restrict__ cs)
{
    const int z   = blockIdx.z;
    const int tid = threadIdx.x;

    if (z == 3) {                    // cast hs: 256 blocks x 16384 elements
        const int bx = blockIdx.y * 16 + blockIdx.x;
        #pragma unroll
        for (int c = 0; c < 16; ++c) {
            const int idx = bx * 16384 + (c * 256 + tid) * 4;
            float4 v = *(const float4*)&hs[idx];
            ushort4 o;
            o.x = f2b(v.x); o.y = f2b(v.y); o.z = f2b(v.z); o.w = f2b(v.w);
            *(ushort4*)&hsb[idx] = o;
        }
        return;
    }
    if (z == 4) {                    // rope table: 128 blocks x 256 entries
        const int bx = blockIdx.y * 16 + blockIdx.x;
        if (bx < 128) {
            const int id = bx * 256 + tid;     // 0..32767
            const int s = id >> 5, d = id & 31;
            const float ang = freqs[s * NDH + d];
            float sn, cn;
            sincosf(ang, &sn, &cn);
            cs[id] = make_float2(cn, sn);
        }
        return;
    }

    // wt transpose
    const float* __restrict__ W = (z == 0) ? Wq : (z == 1) ? Wk : Wv;
    __shared__ float t[64][65];
    const int k0 = blockIdx.x * 64, n0 = blockIdx.y * 64;
    #pragma unroll
    for (int c = 0; c < 16; ++c) {
        const int flat = c * 256 + tid;
        const int r = flat >> 6, cc = flat & 63;
        t[r][cc] = W[(size_t)(k0 + r) * NHID + n0 + cc];
    }
    __syncthreads();
    #pragma unroll
    for (int c = 0; c < 16; ++c) {
        const int flat = c * 256 + tid;
        const int r = flat >> 6, cc = flat & 63;
        wt[(size_t)(z * 1024 + n0 + r) * NHID + k0 + cc] = f2b(t[cc][r]);
    }
}

// ---------------------------------------------------------------------------
// Fused GEMM, bf16 MFMA, 128x128 tile, BK=32 DOUBLE-BUFFERED (one barrier
// per iter; prefetch issued after the barrier flies across the whole compute
// phase). LDS XOR swizzle: slot = chunk ^ ((row>>1)&3) -> <=2-way (free).
// blockIdx.x < 16 : q/k tiles  C = HS . W^T   (fused bias + table-RoPE)
// blockIdx.x >= 16: v^T tiles  C = Wv^T . HS^T (fused bias), V stored
//                   TRANSPOSED [b][h][d][s].
// Epilogue restages the result tile through LDS (row stride 132) and stores
// 8 coalesced global_store_dwordx4 per thread. Accumulation order identical
// to rounds 6/7 -> bit-identical output.
// ---------------------------------------------------------------------------
__global__ __launch_bounds__(256) void fused_gemm_kernel(
    const unsigned short* __restrict__ hsb,   // [4096][1024] bf16
    const unsigned short* __restrict__ wt,    // [3072][1024] bf16  ([n][k])
    const float2* __restrict__ cs,            // [1024][32] (cos,sin)
    const float* __restrict__ bq, const float* __restrict__ bk,
    const float* __restrict__ bv,
    unsigned short* __restrict__ qkv)
{
    // LDS map (shorts): A0[0,4096) A1[4096,8192) B0[8192,12288) B1[12288,16384)
    // epilogue reuses the whole 16896-short block as E[128][132].
    __shared__ short SH[16896];      // 33 KB

    const int tid  = threadIdx.x;
    const int lane = tid & 63;
    const int wv   = __builtin_amdgcn_readfirstlane(tid >> 6);
    const bool vmode = (blockIdx.x >= 16);

    const unsigned short* Amat;
    const unsigned short* Bmat;
    int a_base, b_base, m0, n0, vb_ = 0;
    if (!vmode) {
        n0 = blockIdx.x * 128;               // 0..2047 (q,k planes)
        m0 = blockIdx.y * 128;               // hs rows
        Amat = hsb;  a_base = m0;
        Bmat = wt;   b_base = n0;
    } else {
        m0  = (blockIdx.x - 16) * 128;       // v-channel rows 0..1023
        vb_ = blockIdx.y >> 3;               // batch
        n0  = (blockIdx.y & 7) * 128;        // s
        Amat = wt;   a_base = 2048 + m0;
        Bmat = hsb;  b_base = vb_ * 1024 + n0;
    }

    // staging: tile = 8 KB = 8 chunks of 1 KB; wave wv owns chunks 2wv,2wv+1.
    // 1 KB chunk = 16 rows x 32 shorts. lane i -> row i>>2, slot i&3,
    // swizzled global k-chunk = (i&3) ^ ((i>>3)&3).
    const int ri  = lane >> 2;                            // 0..15
    const int kcs = (((lane & 3) ^ ((lane >> 3) & 3))) * 8;
    const unsigned short* gA[2];
    const unsigned short* gB[2];
    int lAo[2], lBo[2];
    #pragma unroll
    for (int j = 0; j < 2; ++j) {
        const int L = 2 * wv + j;
        gA[j] = Amat + (size_t)(a_base + L * 16 + ri) * NHID + kcs;
        gB[j] = Bmat + (size_t)(b_base + L * 16 + ri) * NHID + kcs;
        lAo[j] = L * 512;                    // within an A buffer
        lBo[j] = 8192 + L * 512;             // within LDS, B0 base
    }

    const int R  = (wv & 1) * 64;
    const int CW = (wv >> 1) * 64;
    const int c0 = lane & 15;
    const int g  = lane >> 4;
    const int swz = (g ^ ((c0 >> 1) & 3)) * 8;           // fragment k slot
    int aoff[4], boff[4];
    #pragma unroll
    for (int i = 0; i < 4; ++i) {
        aoff[i] = (R  + 16 * i + c0) * 32 + swz;
        boff[i] = 8192 + (CW + 16 * i + c0) * 32 + swz;
    }

    f32x4 acc[4][4] = {};

    // prologue: stage k-slab 0 into buffer 0
    #pragma unroll
    for (int j = 0; j < 2; ++j) {
        gload16(gA[j], SH + lAo[j]);
        gload16(gB[j], SH + lBo[j]);
    }
    __syncthreads();                         // buf0 landed

    for (int it = 0; it < 32; ++it) {
        const int cur = (it & 1) * 4096;
        if (it + 1 < 32) {
            const int nxt = ((it + 1) & 1) * 4096;
            const int ko  = (it + 1) * 32;
            #pragma unroll
            for (int j = 0; j < 2; ++j) {
                gload16(gA[j] + ko, SH + nxt + lAo[j]);
                gload16(gB[j] + ko, SH + nxt + lBo[j]);
            }
        }
        bf16x8 af[4], bfr[4];
        #pragma unroll
        for (int i = 0; i < 4; ++i) af[i]  = *(const bf16x8*)&SH[cur + aoff[i]];
        #pragma unroll
        for (int j = 0; j < 4; ++j) bfr[j] = *(const bf16x8*)&SH[cur + boff[j]];
        #pragma unroll
        for (int i = 0; i < 4; ++i)
            #pragma unroll
            for (int j = 0; j < 4; ++j)
                acc[i][j] = __builtin_amdgcn_mfma_f32_16x16x32_bf16(
                    af[i], bfr[j], acc[i][j], 0, 0, 0);
        __syncthreads();   // reads done (next prefetch may overwrite) + drains prefetch
    }

    // ---- epilogue: compute (bit-identical), restage via LDS [128][132] ----
    unsigned short* E = (unsigned short*)SH;
    const int qrow4 = (lane >> 4) * 4;

    if (!vmode) {
        const int z  = n0 >> 10;
        const int hd = ((n0 & 1023) + CW) >> 6;
        const float* __restrict__ bb = (z == 0) ? bq : bk;
        const float b0 = bb[hd * 64 + c0];
        const float b1 = bb[hd * 64 + c0 + 16];
        const float b2 = bb[hd * 64 + c0 + 32];
        const float b3 = bb[hd * 64 + c0 + 48];

        #pragma unroll
        for (int i = 0; i < 4; ++i) {
            #pragma unroll
            for (int r = 0; r < 4; ++r) {
                const int ml = R + qrow4 + 16 * i + r;      // local row
                const int s  = (m0 + ml) & 1023;
                float o0 = acc[i][0][r] + b0;
                float o1 = acc[i][1][r] + b1;
                float o2 = acc[i][2][r] + b2;
                float o3 = acc[i][3][r] + b3;
                const float2 cs0 = cs[s * 32 + c0];
                const float2 cs1 = cs[s * 32 + c0 + 16];
                unsigned short* e = E + ml * 132 + CW + c0;
                e[0]  = f2b(o0 * cs0.x - o2 * cs0.y);
                e[16] = f2b(o1 * cs1.x - o3 * cs1.y);
                e[32] = f2b(o2 * cs0.x + o0 * cs0.y);
                e[48] = f2b(o3 * cs1.x + o1 * cs1.y);
            }
        }
        __syncthreads();             // E complete

        const int hd0 = (n0 & 1023) >> 6;
        unsigned short* __restrict__ base = qkv + (size_t)z * QKV_PLANE;
        #pragma unroll
        for (int c = 0; c < 8; ++c) {
            const int chunk = c * 256 + tid;   // 0..2047
            const int row   = chunk >> 4;      // local m
            const int col16 = chunk & 15;      // 16B chunk within row
            const int m     = m0 + row;
            const int bidx  = m >> 10;
            const int s     = m & 1023;
            const int head  = hd0 + (col16 >> 3);
            const int d     = (col16 & 7) * 8;
            u16x8 v = *(const u16x8*)&E[row * 132 + col16 * 8];
            *(u16x8*)&base[(((size_t)bidx * NH + head) * NS + s) * NDH + d] = v;
        }
    } else {
        #pragma unroll
        for (int i = 0; i < 4; ++i) {
            #pragma unroll
            for (int r = 0; r < 4; ++r) {
                const int ml  = R + qrow4 + 16 * i + r;     // local d-channel
                const float bvm = bv[m0 + ml];
                unsigned short* e = E + ml * 132 + CW + c0;
                e[0]  = f2b(acc[i][0][r] + bvm);
                e[16] = f2b(acc[i][1][r] + bvm);
                e[32] = f2b(acc[i][2][r] + bvm);
                e[48] = f2b(acc[i][3][r] + bvm);
            }
        }
        __syncthreads();             // E complete

        unsigned short* __restrict__ vplane = qkv + 2 * (size_t)QKV_PLANE;
        #pragma unroll
        for (int c = 0; c < 8; ++c) {
            const int chunk = c * 256 + tid;
            const int row   = chunk >> 4;      // local d-channel
            const int col16 = chunk & 15;      // s chunk
            u16x8 v = *(const u16x8*)&E[row * 132 + col16 * 8];
            *(u16x8*)&vplane[((size_t)(vb_ * 1024 + m0 + row)) * NS
                             + n0 + col16 * 8] = v;
        }
    }
}

// ---------------------------------------------------------------------------
// Flash attention, bf16 MFMA, DOUBLE-BUFFERED K/V staging (one barrier/iter).
// Block = 256 thr (4 waves), Q-tile 128 rows of one (b,h); wave w owns
// qrows [w*32, w*32+32) -> 2x work per wave, 1.8x less LDS-read per unit
// work (kf/vf tile reads amortized over 32 qrows instead of 16).
// grid (8,16,4) = 512 blocks -> 2 blocks/CU, 8 waves/CU.
//
// S^T = K.Q^T; exp2-domain no-max softmax (mask pre-scaled by log2e; masked
// keys -> exp2(-1.4e9) = 0 exactly). P in LDS [qrow][key], wave-private.
// Fully-masked K-tiles skipped (mask monotone; exact).
// XOR 16B-chunk swizzle on K/V/P (slot = chunk ^ (row&7)).
// ---------------------------------------------------------------------------
__global__ __launch_bounds__(256) void attn_kernel(
    const unsigned short* __restrict__ qkv, const float* __restrict__ mask,
    float* __restrict__ out)
{
    const int qt = blockIdx.x, h = blockIdx.y, b = blockIdx.z;
    const unsigned short* qp  = qkv + ((size_t)(b * NH + h) * NS) * NDH;      // [s][d]
    const unsigned short* kp  = qp + QKV_PLANE;                               // [s][d]
    const unsigned short* vtp = qkv + 2 * (size_t)QKV_PLANE
                              + ((size_t)(b * NH + h) * NDH) * NS;            // [d][s]

    __shared__ unsigned short KsA[2 * 4096];  // 16 KB, 2 bufs, swizzled [key][dchunk]
    __shared__ unsigned short VtA[2 * 4096];  // 16 KB, 2 bufs, swizzled [d][keychunk]
    __shared__ unsigned short PsA[128 * 64];  // 16 KB swizzled [qrow][keychunk]
    __shared__ float Mk[1024];                // mask * log2e
    __shared__ float Ll[128];                 // row sums

    const int tid  = threadIdx.x;
    const int lane = tid & 63;
    const int w    = __builtin_amdgcn_readfirstlane(tid >> 6);   // 0..3
    const int c0   = lane & 15;
    const int g    = lane >> 4;          // 0..3
    const int sw7  = c0 & 7;
    const float C1 = 0.125f * 1.44269504f;

    // ---- staging: wave w stages K chunks {2w,2w+1} and V chunks {2w,2w+1} ----
    const int i8 = lane >> 3, c8 = lane & 7;
    const int gsw = (c8 ^ i8) * 8;                   // swizzled element offset
    const unsigned short* gk[2];
    const unsigned short* gv[2];
    int lko[2], lvo[2];
    #pragma unroll
    for (int j = 0; j < 2; ++j) {
        const int L = 2 * w + j;
        gk[j] = kp  + (size_t)(L * 8 + i8) * NDH + gsw;
        gv[j] = vtp + (size_t)(L * 8 + i8) * NS  + gsw;
        lko[j] = L * 512;
        lvo[j] = L * 512;
    }

    // prologue: stage K/V tile 0 into buffer 0 (flies during mask/Q setup)
    #pragma unroll
    for (int j = 0; j < 2; ++j) {
        gload16(gk[j], KsA + lko[j]);
        gload16(gv[j], VtA + lvo[j]);
    }

    // ---- mask * log2e -> LDS (4 per thread) ----
    {
        const int i = tid * 4;
        float4 mv = *(const float4*)&mask[(size_t)b * NS + i];
        Mk[i]     = mv.x * 1.44269504f;
        Mk[i + 1] = mv.y * 1.44269504f;
        Mk[i + 2] = mv.z * 1.44269504f;
        Mk[i + 3] = mv.w * 1.44269504f;
    }

    // ---- Q fragments (B-operand, loop-invariant): qrow = qt*128+w*32+nt*16+c0
    bf16x8 qf[2][2];
    #pragma unroll
    for (int nt = 0; nt < 2; ++nt)
        #pragma unroll
        for (int ks = 0; ks < 2; ++ks)
            qf[nt][ks] = *(const bf16x8*)&qp[
                (size_t)(qt * 128 + w * 32 + nt * 16 + c0) * NDH + g * 8 + ks * 32];

    // ---- loop-invariant LDS addresses (shorts, within one buffer) ----
    int kaddr[4][2], pw[2][4], pr[2][2];
    #pragma unroll
    for (int mt = 0; mt < 4; ++mt)
        #pragma unroll
        for (int ks = 0; ks < 2; ++ks)
            kaddr[mt][ks] = (mt * 16 + c0) * 64 + ((g + ks * 4) ^ sw7) * 8;
    #pragma unroll
    for (int nt = 0; nt < 2; ++nt)
        #pragma unroll
        for (int mt = 0; mt < 4; ++mt)
            pw[nt][mt] = (w * 32 + nt * 16 + c0) * 64
                       + ((2 * mt + (g >> 1)) ^ sw7) * 8 + (g & 1) * 4;
    #pragma unroll
    for (int mt = 0; mt < 2; ++mt)
        #pragma unroll
        for (int ks = 0; ks < 2; ++ks)
            pr[mt][ks] = (w * 32 + mt * 16 + c0) * 64 + ((g + ks * 4) ^ sw7) * 8;

    __syncthreads();                       // buf0 + Mk ready

    // ---- uniform tile bound: skip fully-masked tiles (mask monotone) ----
    int ktmax = 16;
    while (ktmax > 1 && Mk[(ktmax - 1) * 64] < -1.0f) --ktmax;

    float lrow[2] = { 0.f, 0.f };
    f32x4 O[2][4] = {};

    for (int kt = 0; kt < ktmax; ++kt) {
        const int cur = (kt & 1) * 4096;
        if (kt + 1 < ktmax) {
            const int nxt = ((kt + 1) & 1) * 4096;
            const size_t ko = (size_t)(kt + 1) * 64;
            #pragma unroll
            for (int j = 0; j < 2; ++j) {
                gload16(gk[j] + ko * NDH, KsA + nxt + lko[j]);
                gload16(gv[j] + ko,       VtA + nxt + lvo[j]);
            }
        }

        // ---- S^T = K . Q^T + softmax numerator + P, per qrow-group nt ----
        bf16x8 kf[4][2];
        #pragma unroll
        for (int mt = 0; mt < 4; ++mt)
            #pragma unroll
            for (int ks = 0; ks < 2; ++ks)
                kf[mt][ks] = *(const bf16x8*)&KsA[cur + kaddr[mt][ks]];

        #pragma unroll
        for (int nt = 0; nt < 2; ++nt) {
            f32x4 S[4];
            #pragma unroll
            for (int mt = 0; mt < 4; ++mt) {
                f32x4 a = {};
                a = __builtin_amdgcn_mfma_f32_16x16x32_bf16(kf[mt][0], qf[nt][0], a, 0, 0, 0);
                a = __builtin_amdgcn_mfma_f32_16x16x32_bf16(kf[mt][1], qf[nt][1], a, 0, 0, 0);
                S[mt] = a;
            }
            float psum = 0.f;
            #pragma unroll
            for (int mt = 0; mt < 4; ++mt) {
                float4 mv = *(const float4*)&Mk[kt * 64 + mt * 16 + g * 4];
                float p0 = fexp2(S[mt][0] * C1 + mv.x);
                float p1 = fexp2(S[mt][1] * C1 + mv.y);
                float p2 = fexp2(S[mt][2] * C1 + mv.z);
                float p3 = fexp2(S[mt][3] * C1 + mv.w);
                psum += (p0 + p1) + (p2 + p3);
                uint2 u;
                u.x = f2b2(p0, p1);
                u.y = f2b2(p2, p3);
                *(uint2*)&PsA[pw[nt][mt]] = u;   // ds_write_b64, wave-private
            }
            lrow[nt] += psum;
        }

        // ---- O += P . V ----
        bf16x8 pf[2][2], vf[4][2];
        #pragma unroll
        for (int mt = 0; mt < 2; ++mt)
            #pragma unroll
            for (int ks = 0; ks < 2; ++ks)
                pf[mt][ks] = *(const bf16x8*)&PsA[pr[mt][ks]];
        #pragma unroll
        for (int nd = 0; nd < 4; ++nd)
            #pragma unroll
            for (int ks = 0; ks < 2; ++ks)
                vf[nd][ks] = *(const bf16x8*)&VtA[cur + kaddr[nd][ks]];
        #pragma unroll
        for (int mt = 0; mt < 2; ++mt)
            #pragma unroll
            for (int nd = 0; nd < 4; ++nd) {
                f32x4 o = O[mt][nd];
                o = __builtin_amdgcn_mfma_f32_16x16x32_bf16(pf[mt][0], vf[nd][0], o, 0, 0, 0);
                o = __builtin_amdgcn_mfma_f32_16x16x32_bf16(pf[mt][1], vf[nd][1], o, 0, 0, 0);
                O[mt][nd] = o;
            }

        __syncthreads();   // K/V reads done (next prefetch overwrites) + drains prefetch
    }

    // ---- final l reduction + normalize + store ----
    #pragma unroll
    for (int nt = 0; nt < 2; ++nt) {
        lrow[nt] += __shfl_xor(lrow[nt], 16);
        lrow[nt] += __shfl_xor(lrow[nt], 32);
        if (g == 0) Ll[w * 32 + nt * 16 + c0] = lrow[nt];  // same-wave LDS
    }
    #pragma unroll
    for (int mt = 0; mt < 2; ++mt) {
        float4 lv4 = *(const float4*)&Ll[w * 32 + mt * 16 + g * 4];
        float inv[4];
        #pragma unroll
        for (int r = 0; r < 4; ++r) inv[r] = 1.0f / ((const float*)&lv4)[r];
        #pragma unroll
        for (int nd = 0; nd < 4; ++nd)
            #pragma unroll
            for (int r = 0; r < 4; ++r) {
                const int row = qt * 128 + w * 32 + mt * 16 + g * 4 + r;
                const int col = h * 64 + nd * 16 + c0;
                out[((size_t)b * NS + row) * NHID + col] = O[mt][nd][r] * inv[r];
            }
    }
}

// ---------------------------------------------------------------------------
extern "C" void kernel_launch(void* const* d_in, const int* in_sizes, int n_in,
                              void* d_out, int out_size, void* d_ws, size_t ws_size,
                              hipStream_t stream) {
    const float* hs    = (const float*)d_in[0];
    const float* mask  = (const float*)d_in[1];
    const float* freqs = (const float*)d_in[2];
    const float* Wq    = (const float*)d_in[3];
    const float* bq    = (const float*)d_in[4];
    const float* Wk    = (const float*)d_in[5];
    const float* bk    = (const float*)d_in[6];
    const float* Wv    = (const float*)d_in[7];
    const float* bv    = (const float*)d_in[8];
    float* out = (float*)d_out;

    // workspace: qkv bf16 25.2MB | hsb bf16 8.4MB | wt bf16 6.3MB | cs 256KB
    char* ws = (char*)d_ws;
    unsigned short* qkvb = (unsigned short*)ws;
    unsigned short* hsb  = (unsigned short*)(ws + 25165824);
    unsigned short* wtb  = (unsigned short*)(ws + 33554432);
    float2*         csb  = (float2*)       (ws + 39845888);

    prep_kernel<<<dim3(16, 16, 5), 256, 0, stream>>>(hs, freqs, Wq, Wk, Wv,
                                                     hsb, wtb, csb);
    fused_gemm_kernel<<<dim3(24, 32), 256, 0, stream>>>(hsb, wtb, csb,
                                                        bq, bk, bv, qkvb);
    attn_kernel<<<dim3(NS / 128, NH, NB), 256, 0, stream>>>(qkvb, mask, out);
}

// Round 9
// 161.438 us; speedup vs baseline: 1.0169x; 1.0169x over previous
//
#include <hip/hip_runtime.h>
#include <hip/hip_bf16.h>
#include <cmath>

#define NB   4
#define NS   1024
#define NHID 1024
#define NH   16
#define NDH  64
#define QKV_PLANE (NB * NH * NS * NDH)   // elements per q/k/v plane

typedef __attribute__((ext_vector_type(8))) short bf16x8;
typedef __attribute__((ext_vector_type(4))) float f32x4;
typedef __attribute__((ext_vector_type(8))) unsigned short u16x8;

typedef __attribute__((address_space(1))) const void gv_t;
typedef __attribute__((address_space(3))) void       lv_t;

__device__ __forceinline__ void gload16(const void* g, void* l) {
    // async global->LDS, 16B/lane; LDS dest = wave-uniform base + lane*16,
    // global address is per-lane arbitrary (lets us swizzle the LDS layout).
    __builtin_amdgcn_global_load_lds((gv_t*)g, (lv_t*)l, 16, 0, 0);
}

__device__ __forceinline__ unsigned short f2b(float f) {
    union { float f; unsigned int u; } v; v.f = f;
    unsigned int r = (v.u + 0x7fff + ((v.u >> 16) & 1)) >> 16;   // RNE
    return (unsigned short)r;
}

// packed fp32x2 -> bf16x2 (RNE); lo 16 bits = a
__device__ __forceinline__ unsigned int f2b2(float a, float b) {
    __hip_bfloat162 h = __float22bfloat162_rn(make_float2(a, b));
    union { __hip_bfloat162 h; unsigned int u; } v; v.h = h;
    return v.u;
}

__device__ __forceinline__ float fexp2(float x) {
#if __has_builtin(__builtin_amdgcn_exp2f)
    return __builtin_amdgcn_exp2f(x);
#else
    return exp2f(x);
#endif
}

// ---------------------------------------------------------------------------
// Prep (single launch, grid (16,16,5)):
//  z<3 : cast+transpose Wq/Wk/Wv [K][N] fp32 -> wt [z*1024+n][k] bf16
//  z==3: cast hidden_states fp32 -> bf16 row-major [4096][1024]
//  z==4: RoPE table cs[s][d] = (cos,sin)(freqs[s][d]), d<32  (float2[1024][32])
// ---------------------------------------------------------------------------
__global__ __launch_bounds__(256) void prep_kernel(
    const float* __restrict__ hs, const float* __restrict__ freqs,
    const float* __restrict__ Wq, const float* __restrict__ Wk,
    const float* __restrict__ Wv,
    unsigned short* __restrict__ hsb, unsigned short* __restrict__ wt,
    float2* __restrict__ cs)
{
    const int z   = blockIdx.z;
    const int tid = threadIdx.x;

    if (z == 3) {                    // cast hs: 256 blocks x 16384 elements
        const int bx = blockIdx.y * 16 + blockIdx.x;
        #pragma unroll
        for (int c = 0; c < 16; ++c) {
            const int idx = bx * 16384 + (c * 256 + tid) * 4;
            float4 v = *(const float4*)&hs[idx];
            ushort4 o;
            o.x = f2b(v.x); o.y = f2b(v.y); o.z = f2b(v.z); o.w = f2b(v.w);
            *(ushort4*)&hsb[idx] = o;
        }
        return;
    }
    if (z == 4) {                    // rope table: 128 blocks x 256 entries
        const int bx = blockIdx.y * 16 + blockIdx.x;
        if (bx < 128) {
            const int id = bx * 256 + tid;     // 0..32767
            const int s = id >> 5, d = id & 31;
            const float ang = freqs[s * NDH + d];
            float sn, cn;
            sincosf(ang, &sn, &cn);
            cs[id] = make_float2(cn, sn);
        }
        return;
    }

    // wt transpose
    const float* __restrict__ W = (z == 0) ? Wq : (z == 1) ? Wk : Wv;
    __shared__ float t[64][65];
    const int k0 = blockIdx.x * 64, n0 = blockIdx.y * 64;
    #pragma unroll
    for (int c = 0; c < 16; ++c) {
        const int flat = c * 256 + tid;
        const int r = flat >> 6, cc = flat & 63;
        t[r][cc] = W[(size_t)(k0 + r) * NHID + n0 + cc];
    }
    __syncthreads();
    #pragma unroll
    for (int c = 0; c < 16; ++c) {
        const int flat = c * 256 + tid;
        const int r = flat >> 6, cc = flat & 63;
        wt[(size_t)(z * 1024 + n0 + r) * NHID + k0 + cc] = f2b(t[cc][r]);
    }
}

// ---------------------------------------------------------------------------
// Fused GEMM (round-7 exact revert), bf16 MFMA, 128x128 tile, BK=64,
// global_load_lds w=16, LDS XOR-swizzled -> conflict-free ds_read_b128.
// blockIdx.x < 16 : q/k tiles  C = HS . W^T   (fused bias + table-RoPE)
// blockIdx.x >= 16: v^T tiles  C = Wv^T . HS^T (fused bias), V stored
//                   TRANSPOSED [b][h][d][s].
// Epilogue restages the result tile through LDS (row stride 132) and stores
// 8 coalesced global_store_dwordx4 per thread. Bit-identical numerics.
// ---------------------------------------------------------------------------
__global__ __launch_bounds__(256) void fused_gemm_kernel(
    const unsigned short* __restrict__ hsb,   // [4096][1024] bf16
    const unsigned short* __restrict__ wt,    // [3072][1024] bf16  ([n][k])
    const float2* __restrict__ cs,            // [1024][32] (cos,sin)
    const float* __restrict__ bq, const float* __restrict__ bk,
    const float* __restrict__ bv,
    unsigned short* __restrict__ qkv)
{
    __shared__ short SH[16896];      // 33 KB: K-loop uses first 32 KB (As|Bs),
    short* As = SH;                  //        epilogue restage uses [128][132]
    short* Bs = SH + 8192;

    const int tid  = threadIdx.x;
    const int lane = tid & 63;
    const int wv   = __builtin_amdgcn_readfirstlane(tid >> 6);
    const bool vmode = (blockIdx.x >= 16);

    const unsigned short* Amat;
    const unsigned short* Bmat;
    int a_base, b_base, m0, n0, vb_ = 0;
    if (!vmode) {
        n0 = blockIdx.x * 128;               // 0..2047 (q,k planes)
        m0 = blockIdx.y * 128;               // hs rows
        Amat = hsb;  a_base = m0;
        Bmat = wt;   b_base = n0;
    } else {
        m0  = (blockIdx.x - 16) * 128;       // v-channel rows 0..1023
        vb_ = blockIdx.y >> 3;               // batch
        n0  = (blockIdx.y & 7) * 128;        // s
        Amat = wt;   a_base = 2048 + m0;
        Bmat = hsb;  b_base = vb_ * 1024 + n0;
    }

    // staging: wave wv owns 8-row groups L = 4*wv..4*wv+3 of A and B.
    // lane i -> row L*8 + (i>>3), swizzled k-chunk ((i&7) ^ (i>>3)) * 8
    const int ri  = lane >> 3;               // 0..7
    const int kcs = ((lane & 7) ^ ri) * 8;   // swizzled k-offset (shorts)
    const unsigned short* gA[4];
    const unsigned short* gB[4];
    short* lA[4];
    short* lB[4];
    #pragma unroll
    for (int j = 0; j < 4; ++j) {
        const int L = 4 * wv + j;
        gA[j] = Amat + (size_t)(a_base + L * 8 + ri) * NHID + kcs;
        gB[j] = Bmat + (size_t)(b_base + L * 8 + ri) * NHID + kcs;
        lA[j] = As + L * 512;                // 8 rows * 64 shorts
        lB[j] = Bs + L * 512;
    }

    const int R  = (wv & 1) * 64;
    const int CW = (wv >> 1) * 64;
    const int c0 = lane & 15;
    const int g  = lane >> 4;
    const int sw7 = c0 & 7;
    int aoff[4][2], boff[4][2];
    #pragma unroll
    for (int i = 0; i < 4; ++i)
        #pragma unroll
        for (int ks = 0; ks < 2; ++ks) {
            aoff[i][ks] = (R  + 16 * i + c0) * 64 + ((g + 4 * ks) ^ sw7) * 8;
            boff[i][ks] = (CW + 16 * i + c0) * 64 + ((g + 4 * ks) ^ sw7) * 8;
        }

    f32x4 acc[4][4] = {};

    for (int k0 = 0; k0 < NHID; k0 += 64) {
        __syncthreads();
        #pragma unroll
        for (int j = 0; j < 4; ++j) {
            gload16(gA[j] + k0, lA[j]);
            gload16(gB[j] + k0, lB[j]);
        }
        __syncthreads();
        #pragma unroll
        for (int ks = 0; ks < 2; ++ks) {
            bf16x8 af[4], bfr[4];
            #pragma unroll
            for (int i = 0; i < 4; ++i) af[i]  = *(const bf16x8*)&As[aoff[i][ks]];
            #pragma unroll
            for (int j = 0; j < 4; ++j) bfr[j] = *(const bf16x8*)&Bs[boff[j][ks]];
            #pragma unroll
            for (int i = 0; i < 4; ++i)
                #pragma unroll
                for (int j = 0; j < 4; ++j)
                    acc[i][j] = __builtin_amdgcn_mfma_f32_16x16x32_bf16(
                        af[i], bfr[j], acc[i][j], 0, 0, 0);
        }
    }

    // ---- epilogue: compute (bit-identical), restage via LDS [128][132] ----
    __syncthreads();                 // all waves done reading As/Bs
    unsigned short* E = (unsigned short*)SH;
    const int qrow4 = (lane >> 4) * 4;

    if (!vmode) {
        const int z  = n0 >> 10;
        const int hd = ((n0 & 1023) + CW) >> 6;
        const float* __restrict__ bb = (z == 0) ? bq : bk;
        const float b0 = bb[hd * 64 + c0];
        const float b1 = bb[hd * 64 + c0 + 16];
        const float b2 = bb[hd * 64 + c0 + 32];
        const float b3 = bb[hd * 64 + c0 + 48];

        #pragma unroll
        for (int i = 0; i < 4; ++i) {
            #pragma unroll
            for (int r = 0; r < 4; ++r) {
                const int ml = R + qrow4 + 16 * i + r;      // local row
                const int s  = (m0 + ml) & 1023;
                float o0 = acc[i][0][r] + b0;
                float o1 = acc[i][1][r] + b1;
                float o2 = acc[i][2][r] + b2;
                float o3 = acc[i][3][r] + b3;
                const float2 cs0 = cs[s * 32 + c0];
                const float2 cs1 = cs[s * 32 + c0 + 16];
                unsigned short* e = E + ml * 132 + CW + c0;
                e[0]  = f2b(o0 * cs0.x - o2 * cs0.y);
                e[16] = f2b(o1 * cs1.x - o3 * cs1.y);
                e[32] = f2b(o2 * cs0.x + o0 * cs0.y);
                e[48] = f2b(o3 * cs1.x + o1 * cs1.y);
            }
        }
        __syncthreads();             // E complete

        const int hd0 = (n0 & 1023) >> 6;
        unsigned short* __restrict__ base = qkv + (size_t)z * QKV_PLANE;
        #pragma unroll
        for (int c = 0; c < 8; ++c) {
            const int chunk = c * 256 + tid;   // 0..2047
            const int row   = chunk >> 4;      // local m
            const int col16 = chunk & 15;      // 16B chunk within row
            const int m     = m0 + row;
            const int bidx  = m >> 10;
            const int s     = m & 1023;
            const int head  = hd0 + (col16 >> 3);
            const int d     = (col16 & 7) * 8;
            u16x8 v = *(const u16x8*)&E[row * 132 + col16 * 8];
            *(u16x8*)&base[(((size_t)bidx * NH + head) * NS + s) * NDH + d] = v;
        }
    } else {
        #pragma unroll
        for (int i = 0; i < 4; ++i) {
            #pragma unroll
            for (int r = 0; r < 4; ++r) {
                const int ml  = R + qrow4 + 16 * i + r;     // local d-channel
                const float bvm = bv[m0 + ml];
                unsigned short* e = E + ml * 132 + CW + c0;
                e[0]  = f2b(acc[i][0][r] + bvm);
                e[16] = f2b(acc[i][1][r] + bvm);
                e[32] = f2b(acc[i][2][r] + bvm);
                e[48] = f2b(acc[i][3][r] + bvm);
            }
        }
        __syncthreads();             // E complete

        unsigned short* __restrict__ vplane = qkv + 2 * (size_t)QKV_PLANE;
        #pragma unroll
        for (int c = 0; c < 8; ++c) {
            const int chunk = c * 256 + tid;
            const int row   = chunk >> 4;      // local d-channel
            const int col16 = chunk & 15;      // s chunk
            u16x8 v = *(const u16x8*)&E[row * 132 + col16 * 8];
            *(u16x8*)&vplane[((size_t)(vb_ * 1024 + m0 + row)) * NS
                             + n0 + col16 * 8] = v;
        }
    }
}

// ---------------------------------------------------------------------------
// Flash attention, bf16 MFMA. Block = 256 thr (4 waves), Q-tile 64 rows of
// one (b,h); wave w owns qrows [w*16, w*16+16). K-tile 64 keys.
// grid (16,16,4) = 1024 blocks -> 4 blocks/CU (28 KB LDS), 16 waves/CU:
// four independent barrier groups per CU overlap each other's staging
// latency (the 2-blocks/CU version left the drain exposed).
//
// S^T = K.Q^T; exp2-domain no-max softmax (mask pre-scaled by log2e; masked
// keys -> exp2(-1.4e9) = 0 exactly). P in LDS [qrow][key], wave-private.
// Fully-masked K-tiles skipped (mask monotone; exact). Numerics identical
// to rounds 4/6/7.
// XOR 16B-chunk swizzle on K/V/P (slot = chunk ^ (row&7)).
// ---------------------------------------------------------------------------
__global__ __launch_bounds__(256) void attn_kernel(
    const unsigned short* __restrict__ qkv, const float* __restrict__ mask,
    float* __restrict__ out)
{
    const int qt = blockIdx.x, h = blockIdx.y, b = blockIdx.z;
    const unsigned short* qp  = qkv + ((size_t)(b * NH + h) * NS) * NDH;      // [s][d]
    const unsigned short* kp  = qp + QKV_PLANE;                               // [s][d]
    const unsigned short* vtp = qkv + 2 * (size_t)QKV_PLANE
                              + ((size_t)(b * NH + h) * NDH) * NS;            // [d][s]

    __shared__ unsigned short KsA[64 * 64];   // 8 KB swizzled [key][dchunk]
    __shared__ unsigned short VtA[64 * 64];   // 8 KB swizzled [d][keychunk]
    __shared__ unsigned short PsA[64 * 64];   // 8 KB swizzled [qrow][keychunk]
    __shared__ float Mk[1024];                // mask * log2e
    __shared__ float Ll[64];                  // row sums

    const int tid  = threadIdx.x;
    const int lane = tid & 63;
    const int w    = __builtin_amdgcn_readfirstlane(tid >> 6);   // 0..3
    const int c0   = lane & 15;
    const int g    = lane >> 4;          // 0..3
    const int sw7  = c0 & 7;
    const float C1 = 0.125f * 1.44269504f;

    // ---- mask * log2e -> LDS (4 per thread) ----
    {
        const int i = tid * 4;
        float4 mv = *(const float4*)&mask[(size_t)b * NS + i];
        Mk[i]     = mv.x * 1.44269504f;
        Mk[i + 1] = mv.y * 1.44269504f;
        Mk[i + 2] = mv.z * 1.44269504f;
        Mk[i + 3] = mv.w * 1.44269504f;
    }

    // ---- Q fragments (B-operand, loop-invariant): qrow = qt*64 + w*16 + c0
    bf16x8 qf[2];
    #pragma unroll
    for (int ks = 0; ks < 2; ++ks)
        qf[ks] = *(const bf16x8*)&qp[
            (size_t)(qt * 64 + w * 16 + c0) * NDH + g * 8 + ks * 32];

    // ---- staging: wave w stages K chunks {2w,2w+1}, V chunks {2w,2w+1} ----
    const int i8 = lane >> 3, c8 = lane & 7;
    const int gsw = (c8 ^ i8) * 8;                   // swizzled element offset
    const unsigned short* gk[2];
    const unsigned short* gv[2];
    unsigned short* lk[2];
    unsigned short* lv[2];
    #pragma unroll
    for (int j = 0; j < 2; ++j) {
        const int L = 2 * w + j;
        gk[j] = kp  + (size_t)(L * 8 + i8) * NDH + gsw;
        gv[j] = vtp + (size_t)(L * 8 + i8) * NS  + gsw;
        lk[j] = KsA + L * 512;
        lv[j] = VtA + L * 512;
    }

    // ---- loop-invariant LDS addresses (shorts) ----
    int kaddr[4][2], pw4[4], pr[2];
    #pragma unroll
    for (int mt = 0; mt < 4; ++mt)
        #pragma unroll
        for (int ks = 0; ks < 2; ++ks)
            kaddr[mt][ks] = (mt * 16 + c0) * 64 + ((g + ks * 4) ^ sw7) * 8;
    #pragma unroll
    for (int mt = 0; mt < 4; ++mt)
        pw4[mt] = (w * 16 + c0) * 64 + ((2 * mt + (g >> 1)) ^ sw7) * 8 + (g & 1) * 4;
    #pragma unroll
    for (int ks = 0; ks < 2; ++ks)
        pr[ks] = (w * 16 + c0) * 64 + ((g + ks * 4) ^ sw7) * 8;

    // ---- uniform tile bound: skip fully-masked tiles (mask monotone) ----
    __syncthreads();                       // Mk visible
    int ktmax = 16;
    while (ktmax > 1 && Mk[(ktmax - 1) * 64] < -1.0f) --ktmax;

    float lrow = 0.f;
    f32x4 O[4] = {};

    for (int kt = 0; kt < ktmax; ++kt) {
        __syncthreads();                   // protect K/V from prev-iter reads
        #pragma unroll
        for (int j = 0; j < 2; ++j) {
            gload16(gk[j], lk[j]);
            gload16(gv[j], lv[j]);
            gk[j] += 64 * NDH;             // next 64 keys
            gv[j] += 64;
        }
        __syncthreads();                   // staging landed

        // ---- S^T = K . Q^T  (8 MFMA) ----
        bf16x8 kf[4][2];
        #pragma unroll
        for (int mt = 0; mt < 4; ++mt)
            #pragma unroll
            for (int ks = 0; ks < 2; ++ks)
                kf[mt][ks] = *(const bf16x8*)&KsA[kaddr[mt][ks]];
        f32x4 S[4];
        #pragma unroll
        for (int mt = 0; mt < 4; ++mt) {
            f32x4 a = {};
            a = __builtin_amdgcn_mfma_f32_16x16x32_bf16(kf[mt][0], qf[0], a, 0, 0, 0);
            a = __builtin_amdgcn_mfma_f32_16x16x32_bf16(kf[mt][1], qf[1], a, 0, 0, 0);
            S[mt] = a;
        }

        // ---- softmax numerator: p = exp2(S*C1 + mask2), write P ----
        float psum = 0.f;
        #pragma unroll
        for (int mt = 0; mt < 4; ++mt) {
            float4 mv = *(const float4*)&Mk[kt * 64 + mt * 16 + g * 4];
            float p0 = fexp2(S[mt][0] * C1 + mv.x);
            float p1 = fexp2(S[mt][1] * C1 + mv.y);
            float p2 = fexp2(S[mt][2] * C1 + mv.z);
            float p3 = fexp2(S[mt][3] * C1 + mv.w);
            psum += (p0 + p1) + (p2 + p3);
            uint2 u;
            u.x = f2b2(p0, p1);
            u.y = f2b2(p2, p3);
            *(uint2*)&PsA[pw4[mt]] = u;    // ds_write_b64, wave-private row
        }
        lrow += psum;

        // ---- O += P . V  (8 MFMA) ----
        bf16x8 pf[2], vf[4][2];
        #pragma unroll
        for (int ks = 0; ks < 2; ++ks)
            pf[ks] = *(const bf16x8*)&PsA[pr[ks]];
        #pragma unroll
        for (int nd = 0; nd < 4; ++nd)
            #pragma unroll
            for (int ks = 0; ks < 2; ++ks)
                vf[nd][ks] = *(const bf16x8*)&VtA[kaddr[nd][ks]];
        #pragma unroll
        for (int nd = 0; nd < 4; ++nd) {
            f32x4 o = O[nd];
            o = __builtin_amdgcn_mfma_f32_16x16x32_bf16(pf[0], vf[nd][0], o, 0, 0, 0);
            o = __builtin_amdgcn_mfma_f32_16x16x32_bf16(pf[1], vf[nd][1], o, 0, 0, 0);
            O[nd] = o;
        }
    }

    // ---- final l reduction + normalize + store ----
    lrow += __shfl_xor(lrow, 16);
    lrow += __shfl_xor(lrow, 32);
    if (g == 0) Ll[w * 16 + c0] = lrow;    // same-wave LDS, no barrier needed
    float4 lv4 = *(const float4*)&Ll[w * 16 + g * 4];
    float inv[4];
    #pragma unroll
    for (int r = 0; r < 4; ++r) inv[r] = 1.0f / ((const float*)&lv4)[r];

    #pragma unroll
    for (int nd = 0; nd < 4; ++nd)
        #pragma unroll
        for (int r = 0; r < 4; ++r) {
            const int row = qt * 64 + w * 16 + g * 4 + r;
            const int col = h * 64 + nd * 16 + c0;
            out[((size_t)b * NS + row) * NHID + col] = O[nd][r] * inv[r];
        }
}

// ---------------------------------------------------------------------------
extern "C" void kernel_launch(void* const* d_in, const int* in_sizes, int n_in,
                              void* d_out, int out_size, void* d_ws, size_t ws_size,
                              hipStream_t stream) {
    const float* hs    = (const float*)d_in[0];
    const float* mask  = (const float*)d_in[1];
    const float* freqs = (const float*)d_in[2];
    const float* Wq    = (const float*)d_in[3];
    const float* bq    = (const float*)d_in[4];
    const float* Wk    = (const float*)d_in[5];
    const float* bk    = (const float*)d_in[6];
    const float* Wv    = (const float*)d_in[7];
    const float* bv    = (const float*)d_in[8];
    float* out = (float*)d_out;

    // workspace: qkv bf16 25.2MB | hsb bf16 8.4MB | wt bf16 6.3MB | cs 256KB
    char* ws = (char*)d_ws;
    unsigned short* qkvb = (unsigned short*)ws;
    unsigned short* hsb  = (unsigned short*)(ws + 25165824);
    unsigned short* wtb  = (unsigned short*)(ws + 33554432);
    float2*         csb  = (float2*)       (ws + 39845888);

    prep_kernel<<<dim3(16, 16, 5), 256, 0, stream>>>(hs, freqs, Wq, Wk, Wv,
                                                     hsb, wtb, csb);
    fused_gemm_kernel<<<dim3(24, 32), 256, 0, stream>>>(hsb, wtb, csb,
                                                        bq, bk, bv, qkvb);
    attn_kernel<<<dim3(16, NH, NB), 256, 0, stream>>>(qkvb, mask, out);
}